// Round 6
// baseline (182.341 us; speedup 1.0000x reference)
//
#include <hip/hip_runtime.h>

#define B_ 2
#define C_ 256
#define H_ 56
#define W_ 56
#define N_ 64
#define M_ 8
#define P_ 7
#define Y2_ (H_/2)               // 28 y-row pairs
#define Y4_ (H_/4)               // 14 y-row quads
#define KR_ (1 + M_)             // 9 rois per (b,n): box + 8 ctx unions
#define JPB_ (KR_*4)             // 36 px-pair jobs per (b,n) -> 4608 blocks
#define WROW_ 8                  // padded weight-row stride (7 used + col7 = 0)

typedef _Float16 half2v __attribute__((ext_vector_type(2)));

#if __has_builtin(__builtin_amdgcn_fdot2)
#define FDOT2(a, b, c) __builtin_amdgcn_fdot2((a), (b), (c), false)
#else
static __device__ __forceinline__ float FDOT2(half2v a, half2v b, float c) {
    return fmaf((float)a.x, (float)b.x, fmaf((float)a.y, (float)b.y, c));
}
#endif

// ---- workspace layout (dword-element offsets) ----
#define F_FMT4 0
#define N_FMT4 (B_*Y4_*W_*C_*2)              // 802,816 dw  f16 y-QUAD-packed fmap
#define F_OUTS (F_FMT4 + N_FMT4)
#define N_OUTS (B_*N_*49*C_)                 // 1,605,632 staging out [b][n][py][px][c]
#define WS_ELEMS (F_OUTS + N_OUTS)

// prep kernel block ranges (R2-proven: fused transpose + outS zeroing)
#define PREP_T (B_*Y4_*4*2)                  // 224: (b, y4, cgroup, xhalf) transpose
#define PREP_N (PREP_T + 784)                // + zero outS (784*2048 floats)

// ---------------------------------------------------------------------------
// k_prep (R2-verified): two jobs in one dispatch.
//   [0,224):   COALESCED fm -> fmt4 via LDS tile (112B-run reads, 512B/wave
//              c-contiguous packed stores).
//   [224,1008): zero outS
__global__ __launch_bounds__(256) void k_prep(const float* __restrict__ fm,
                                              float* __restrict__ ws_f) {
    __shared__ float t[28 * 257 + 8];        // [x28][y4][c64], x-stride 257 pad
    int bid = blockIdx.x;
    int tid = (int)threadIdx.x;

    if (bid < PREP_T) {                      // ---- y4 pack-transpose ----
        int xh = bid & 1;
        int cg = (bid >> 1) & 3;
        int y4 = (bid >> 3) % Y4_;
        int b  = (bid >> 3) / Y4_;
        int c0 = cg * 64, x0 = xh * 28;
        for (int e = tid; e < 64 * 4 * 28; e += 256) {
            int c_l = e / 112, rem = e % 112;
            int y_l = rem / 28, x_l = rem % 28;
            t[x_l * 257 + y_l * 64 + c_l] =
                fm[(((size_t)b * C_ + c0 + c_l) * H_ + 4 * y4 + y_l) * W_ + x0 + x_l];
        }
        __syncthreads();
        uint2* dst = (uint2*)ws_f;
        for (int e = tid; e < 28 * 64; e += 256) {
            int x_l = e >> 6, c_l = e & 63;
            const float* p = &t[x_l * 257 + c_l];
            half2v lo, hi; uint2 o;
            lo.x = (_Float16)p[0];   lo.y = (_Float16)p[64];
            hi.x = (_Float16)p[128]; hi.y = (_Float16)p[192];
            o.x = __builtin_bit_cast(unsigned int, lo);
            o.y = __builtin_bit_cast(unsigned int, hi);
            dst[(((size_t)b * Y4_ + y4) * W_ + x0 + x_l) * (size_t)C_ + c0 + c_l] = o;
        }
        return;
    }

    {                                        // ---- zero outS ----
        int tz = (bid - PREP_T) * 256 + tid; // < 200,704
        float4 z = {0.0f, 0.0f, 0.0f, 0.0f};
        float4* dst = (float4*)(ws_f + F_OUTS);
        dst[tz * 2]     = z;
        dst[tz * 2 + 1] = z;
    }
}

// ---------------------------------------------------------------------------
// k_main REGISTER-DIET redesign (R6).  R0-R5 established: latency-bound at
// ~2.5 eff waves/SIMD; ILP can't be added (R4: compiler sinks prefetch; R5:
// forcing it spills — acc[49]+cs[28] eat the register file).  So the state
// is shrunk instead: every job owns a px-PAIR (R2-verified support math,
// now for box rois too -> 36 jobs/(b,n), grid 4608), loop nest is y-outer/
// x-inner so y-weights hoist to 14 regs per y4, and the accumulator is
// acc0/acc1[7] = 14 regs.  No cs[], no live-mask, no x-quad over-read.
// ~50 live VGPRs -> __launch_bounds__(256,8): 8 waves/SIMD, 2x residency;
// TLP hides the per-cell L2 hit (need ~4.3 waves for 200cy over a ~60cy
// body).  Atomic volume = R2's proven 56.4MB (exactly 7 live px-rows/roi).
__global__ __launch_bounds__(256, 8) void k_main(const float* __restrict__ ws_f,
                                                 const float* __restrict__ boxes,
                                                 const float* __restrict__ gt,
                                                 float* __restrict__ outs) {
    __shared__ float        s_wyf[H_][WROW_];      // 1792 B fp32 y staging
    __shared__ unsigned int s_wy2[Y2_ * WROW_];    //  896 B packed half2
    __shared__ float        s_ax[W_][WROW_];       // 1792 B fp32 x-weights

    int bid = blockIdx.x;
    int j   = bid % JPB_;                    // 0..35
    int n   = (bid / JPB_) & (N_ - 1);
    int b   = bid / (JPB_ * N_);
    int k   = j >> 2;                        // 0 = box, 1..8 = ctx union
    int s   = j & 3;                         // px-pair: {0,1}{2,3}{4,5}{6}
    int p0  = 2 * s;                         // p1 = p0+1 (s<3) or p0 (s==3)
    int tid = (int)threadIdx.x;
    int c   = tid;

    // ---- roi coords (wave-uniform scalar loads) ----
    const float* bp = boxes + ((size_t)b * N_ + n) * 4;
    float bx1, by1, bx2, by2;
    if (k == 0) {
        bx1 = bp[0]; by1 = bp[1]; bx2 = bp[2]; by2 = bp[3];
    } else {
        const float* gp = gt + ((size_t)b * M_ + (k - 1)) * 4;
        bx1 = fminf(bp[0], gp[0]); by1 = fminf(bp[1], gp[1]);
        bx2 = fmaxf(bp[2], gp[2]); by2 = fmaxf(bp[3], gp[3]);
    }
    float rw = fmaxf(bx2 - bx1, 1.0f);
    float rh = fmaxf(by2 - by1, 1.0f);

    // ---- in-block weight generation (R0-proven serial column-private) ----
    for (int e = tid; e < H_ * WROW_; e += 256) ((float*)s_wyf)[e] = 0.0f;
    for (int e = tid; e < W_ * WROW_; e += 256) ((float*)s_ax)[e] = 0.0f;
    __syncthreads();

    if (tid < P_) {                          // y samples, column-private
        int p = tid;
        float bin = rh / 7.0f;
        float gf  = ceilf(bin);
        int   g   = (int)gf;
        float ivg = 1.0f / gf;
        float start = by1 + (float)p * bin;
        for (int ss = 0; ss < g; ++ss) {
            float coord = start + ((float)ss + 0.5f) * bin * ivg;
            if (coord < -1.0f || coord > (float)H_) continue;
            float cc = fmaxf(coord, 0.0f);
            int low = (int)floorf(cc);
            int high; float l;
            if (low >= H_ - 1) { low = H_ - 1; high = H_ - 1; l = 0.0f; }
            else               { high = low + 1; l = cc - (float)low; }
            s_wyf[low][p]  += (1.0f - l) * ivg;
            s_wyf[high][p] += l * ivg;
        }
    } else if (tid >= 64 && tid < 64 + P_) { // x samples, column-private
        int p = tid - 64;
        float bin = rw / 7.0f;
        float gf  = ceilf(bin);
        int   g   = (int)gf;
        float ivg = 1.0f / gf;
        float fs  = (k == 0) ? ivg : ivg * (1.0f / (float)M_);
        float start = bx1 + (float)p * bin;
        for (int ss = 0; ss < g; ++ss) {
            float coord = start + ((float)ss + 0.5f) * bin * ivg;
            if (coord < -1.0f || coord > (float)W_) continue;
            float cc = fmaxf(coord, 0.0f);
            int low = (int)floorf(cc);
            int high; float l;
            if (low >= W_ - 1) { low = W_ - 1; high = W_ - 1; l = 0.0f; }
            else               { high = low + 1; l = cc - (float)low; }
            s_ax[low][p]  += (1.0f - l) * fs;
            s_ax[high][p] += l * fs;
        }
    }
    __syncthreads();

    if (tid < Y2_ * WROW_) {                 // pack y fp32 pairs -> half2
        int q2 = tid >> 3, col = tid & 7;
        half2v h;
        if (col < P_) { h.x = (_Float16)s_wyf[2 * q2][col]; h.y = (_Float16)s_wyf[2 * q2 + 1][col]; }
        else          { h.x = (_Float16)0.0f; h.y = (_Float16)0.0f; }
        s_wy2[tid] = __builtin_bit_cast(unsigned int, h);
    }
    __syncthreads();

    // ---- px-pair column support (R2-verified formulas, roi-generic) ----
    float binw = rw * (1.0f / 7.0f);
    float lo_f = bx1 + (float)p0 * binw;             // samples in (lo_f, hi_f)
    int   pe   = (p0 + 1 < P_) ? p0 + 2 : p0 + 1;    // exclusive px end
    float hi_f = bx1 + (float)pe * binw;
    int xs = min(max((int)floorf(fmaxf(lo_f, 0.0f)), 0), W_ - 1);
    int xe = min(max((int)floorf(fminf(hi_f, (float)W_)) + 1, 0), W_ - 1) + 1;
    if (xs >= xe) return;                    // block-uniform, after all barriers

    int ylo = min(max((int)floorf(fmaxf(by1, 0.0f)), 0), H_ - 1);
    int yhi = min(max((int)floorf(by1 + rh) + 1, 0), H_ - 1) + 1;
    int ylo4 = ylo >> 2;                     // quad range covering [ylo,yhi)
    int yhi4 = (yhi + 3) >> 2;               // extra rows have zero weight

    const uint2* f4 = (const uint2*)ws_f + (size_t)b * (Y4_ * W_ * C_);

    float acc0[P_], acc1[P_];
#pragma unroll
    for (int q = 0; q < P_; ++q) { acc0[q] = 0.0f; acc1[q] = 0.0f; }

    for (int y4 = ylo4; y4 < yhi4; ++y4) {
        // hoist this quad's y-weights: 14 half2 registers (broadcast reads)
        uint4 wa = *(const uint4*)&s_wy2[(2 * y4) * WROW_];
        uint4 wb = *(const uint4*)&s_wy2[(2 * y4) * WROW_ + 4];
        uint4 wc = *(const uint4*)&s_wy2[(2 * y4 + 1) * WROW_];
        uint4 wd = *(const uint4*)&s_wy2[(2 * y4 + 1) * WROW_ + 4];
        half2v wlo[7], whi[7];
        wlo[0] = __builtin_bit_cast(half2v, wa.x);
        wlo[1] = __builtin_bit_cast(half2v, wa.y);
        wlo[2] = __builtin_bit_cast(half2v, wa.z);
        wlo[3] = __builtin_bit_cast(half2v, wa.w);
        wlo[4] = __builtin_bit_cast(half2v, wb.x);
        wlo[5] = __builtin_bit_cast(half2v, wb.y);
        wlo[6] = __builtin_bit_cast(half2v, wb.z);
        whi[0] = __builtin_bit_cast(half2v, wc.x);
        whi[1] = __builtin_bit_cast(half2v, wc.y);
        whi[2] = __builtin_bit_cast(half2v, wc.z);
        whi[3] = __builtin_bit_cast(half2v, wc.w);
        whi[4] = __builtin_bit_cast(half2v, wd.x);
        whi[5] = __builtin_bit_cast(half2v, wd.y);
        whi[6] = __builtin_bit_cast(half2v, wd.z);

        const uint2* cp = f4 + ((size_t)(y4 * W_ + xs)) * C_ + c;
        for (int x = xs; x < xe; ++x) {
            uint2 d = *cp;
            cp += C_;
            float2 axv = *(const float2*)&s_ax[x][p0];   // p0 even -> 8B aligned
            half2v va = __builtin_bit_cast(half2v, d.x);
            half2v vb = __builtin_bit_cast(half2v, d.y);
            float t[P_];
#pragma unroll
            for (int py = 0; py < P_; ++py)
                t[py] = FDOT2(whi[py], vb, FDOT2(wlo[py], va, 0.0f));
#pragma unroll
            for (int py = 0; py < P_; ++py) {
                acc0[py] = fmaf(axv.x, t[py], acc0[py]);
                acc1[py] = fmaf(axv.y, t[py], acc1[py]);
            }
        }
    }

    // ---- epilogue: px-pair coalesced wave-atomics into outS ----
    // (s==3: p0==6, axv.y read the zeroed pad col 7 -> acc1 == 0, skipped)
    float* os = outs + ((size_t)b * N_ + n) * (49 * C_) + c;
#pragma unroll
    for (int py = 0; py < P_; ++py)
        atomicAdd(os + (py * P_ + p0) * C_, acc0[py]);
    if (p0 + 1 < P_) {
#pragma unroll
        for (int py = 0; py < P_; ++py)
            atomicAdd(os + (py * P_ + p0 + 1) * C_, acc1[py]);
    }
}

// ---------------------------------------------------------------------------
// k_final: outS [b][n][py][px][c] -> out [b][n][c][py][px] via padded LDS.
// 512 blocks: (bn, 64-channel group) tiles (R1-verified).
__global__ __launch_bounds__(256) void k_final(const float* __restrict__ outs,
                                               float* __restrict__ out) {
    __shared__ float t[49 * 65];             // pad 65: conflict-free transpose
    int bid = blockIdx.x;                    // bn*4 + cg
    int cg  = bid & 3;
    int bn  = bid >> 2;
    int tid = (int)threadIdx.x;
    const float* src = outs + (size_t)bn * (49 * C_) + cg * 64;
    for (int e = tid; e < 49 * 64; e += 256) {
        int q = e >> 6, c = e & 63;
        t[q * 65 + c] = src[q * C_ + c];     // coalesced read
    }
    __syncthreads();
    float* dst = out + (size_t)bn * (C_ * 49) + (size_t)cg * 64 * 49;
    for (int e = tid; e < 64 * 49; e += 256) {
        int c = e / 49, q = e - c * 49;
        dst[e] = t[q * 65 + c];              // coalesced write
    }
}

// ---------------------------------------------------------------------------
extern "C" void kernel_launch(void* const* d_in, const int* in_sizes, int n_in,
                              void* d_out, int out_size, void* d_ws, size_t ws_size,
                              hipStream_t stream) {
    const float* fm    = (const float*)d_in[0];
    const float* boxes = (const float*)d_in[1];
    const float* gt    = (const float*)d_in[2];
    float* ws_f = (float*)d_ws;
    float* out  = (float*)d_out;
    float* outs = ws_f + F_OUTS;

    k_prep<<<PREP_N, 256, 0, stream>>>(fm, ws_f);
    k_main<<<B_ * N_ * JPB_, 256, 0, stream>>>(ws_f, boxes, gt, outs);
    k_final<<<B_ * N_ * 4, 256, 0, stream>>>(outs, out);
}